// Round 17
// baseline (73.665 us; speedup 1.0000x reference)
//
#include <hip/hip_runtime.h>
#include <stdint.h>

// Problem constants: x (4, 8192, 512) f32, A/B (512, 64), h0 scalar.
#define NBATCH 4
#define LSEQ   8192
#define CH     512
#define ORDER  64
#define KTAP   256           // validated R3-R16: tail < 1e-5, threshold 5.86e-3

typedef _Float16 half8  __attribute__((ext_vector_type(8)));
typedef _Float16 half4  __attribute__((ext_vector_type(4)));
typedef float    f32x4  __attribute__((ext_vector_type(4)));
typedef float    f32x16 __attribute__((ext_vector_type(16)));

// Transposed/padded x geometry: column p = PAD0 + row, zeros outside [0,8192).
#define PADP  8512
#define PAD0  279
// 32x32x16 tap windows: T0_w = 16w-17, w=0..17. Row i covers taps
// [i-32, i+255] (each once); Kx zero-padded outside [0,256).
#define NW2   18

#define AFRAG_HALFS  ((size_t)CH * NW2 * 64 * 8)       // 9.4 MB
#define XT_HALFS     ((size_t)CH * NBATCH * PADP)      // 34.9 MB
#define WS_NEED      ((AFRAG_HALFS + XT_HALFS) * 2)

#define NAPREP 128                       // afrag blocks (4 ch each)
#define NXPOSE (133 * 8 * NBATCH)        // xpose blocks (PADP/64 x CH/64 x B)

// fir LDS: xs[16 ch][1312 halves], row stride padded to 2752 B so the XOR
// swizzle (bits 4-6 ^= bits 7-9, max +112 B) never crosses rows. lout[16][260]
// f32 ALIASED onto xs (xs dead after MFMA loop; barrier orders it).
#define XROWB 2752
#define SMEMB (16 * XROWB)   // 44032 B -> 3 blocks/CU
#define LOWB  1040

__device__ __forceinline__ int swz(int b) { return b ^ (((b >> 7) & 7) << 4); }

// ---------------------------------------------------------------------------
// Kernel 1 (fused prep): blocks [0,128) build per-channel 32x32 MFMA
// A-fragments: A_w[i][k] = Kx[16w-17+i-k], lane l: i=l&31, k=8*(l>>5)+e;
// h0 folded into Kx[0]. Blocks [128,128+4256) transpose x to xT[c*4+b][p]
// f16 zero-padded (64x64 LDS tile, proven R8/R16).
// ---------------------------------------------------------------------------
__global__ __launch_bounds__(256) void prep(const float* __restrict__ A,
                                            const float* __restrict__ B,
                                            const float* __restrict__ h0,
                                            const float* __restrict__ x,
                                            _Float16* __restrict__ afr,
                                            _Float16* __restrict__ xT) {
    __shared__ float    Ksh[4][KTAP];
    __shared__ _Float16 tile[64][74];
    const int bid = blockIdx.x;
    if (bid < NAPREP) {
        const int wv = threadIdx.x >> 6, lane = threadIdx.x & 63;
        const int c  = bid * 4 + wv;
        const float a  = A[c * ORDER + lane];
        const float bc = B[c * ORDER + lane];
        const float h0v = h0[0];
        float s = 0.0f;
        for (int t = 0; t < KTAP; ++t) {
            const float s1 = __shfl(s, 0);
            const float bt = (t < ORDER) ? __shfl(bc, t) : 0.0f;
            const float y  = bt + s1;
            float su = __shfl_down(s, 1);
            if (lane == ORDER - 1) su = 0.0f;
            s = su - a * y;
            if (lane == 0) Ksh[wv][t] = (t == 0) ? (y + h0v) : y;
        }
        __syncthreads();
        const int i32 = lane & 31, h = lane >> 5;
        for (int w = 0; w < NW2; ++w) {
            half8 hv;
#pragma unroll
            for (int e = 0; e < 8; ++e) {
                const int t = 16 * w - 17 + i32 - 8 * h - e;
                hv[e] = (_Float16)((t >= 0 && t < KTAP) ? Ksh[wv][t] : 0.0f);
            }
            *reinterpret_cast<half8*>(afr + ((size_t)(c * NW2 + w) * 64 + lane) * 8) = hv;
        }
    } else {
        const int bid2 = bid - NAPREP;
        const int px   = bid2 % 133;
        const int cy   = (bid2 / 133) & 7;
        const int bz   = bid2 / (133 * 8);
        const int p0 = px * 64, c0 = cy * 64, t = threadIdx.x;
        const int cl = (t & 15) * 4;
        const int rl = t >> 4;
#pragma unroll
        for (int pass = 0; pass < 4; ++pass) {
            const int pl = rl + 16 * pass;
            const int r  = p0 + pl - PAD0;
            float4 v = {0.0f, 0.0f, 0.0f, 0.0f};
            if (r >= 0 && r < LSEQ)
                v = *reinterpret_cast<const float4*>(x + ((size_t)bz * LSEQ + r) * CH + c0 + cl);
            tile[pl][cl + 0] = (_Float16)v.x;
            tile[pl][cl + 1] = (_Float16)v.y;
            tile[pl][cl + 2] = (_Float16)v.z;
            tile[pl][cl + 3] = (_Float16)v.w;
        }
        __syncthreads();
        const int pl2 = (t & 15) * 4;
#pragma unroll
        for (int pass = 0; pass < 4; ++pass) {
            const int cc = (t >> 4) + 16 * pass;
            half4 hv;
#pragma unroll
            for (int d = 0; d < 4; ++d) hv[d] = tile[pl2 + d][cc];
            *reinterpret_cast<half4*>(xT + ((size_t)((c0 + cc) * NBATCH + bz)) * PADP + p0 + pl2) = hv;
        }
    }
}

// ---------------------------------------------------------------------------
// Kernel 2: FIR as banded-Toeplitz 32x32x16 MFMA + gelu (R16 skeleton; the
// change: one MFMA covers 1024 n x 16 taps per channel -> 72 ds_read_b128 +
// 72 MFMA per wave vs 144+144 with 16x16x32 — halves the binding LDS pipe).
// Block = 16 ch x 1024 n x 1 batch, grid 1024, chgrp-major XCD swizzle.
// B-frag: 16 contiguous halves at rel 288-16w+32j+8h (j=lane&31, h=lane>>5),
// XOR-swizzled (both stage-write and read) to break the 16-way bank conflict.
// D: col j=lane&31, row i=(reg&3)+8*(reg>>2)+4h; n = n0 + 32j + i.
// Epilogue per 256-tile: lanes with j>>3==ti write gelu -> lout (aliased),
// then R16's proven all-thread float4 gather-store.
// ---------------------------------------------------------------------------
__global__ __launch_bounds__(256) void fir_mfma(const _Float16* __restrict__ xT,
                                                const _Float16* __restrict__ afr,
                                                float* __restrict__ out) {
    __shared__ __align__(16) char smem[SMEMB];          // xs; lout aliases it
    const int gid     = blockIdx.x;
    const int logical = (gid & 7) * 128 + (gid >> 3);   // bijective (1024%8==0)
    const int chgrp   = logical >> 5;                   // 0..31 (XCD-local slab)
    const int rem     = logical & 31;
    const int bb      = rem >> 3;
    const int tg      = rem & 7;

    // ---- stage x window (16 ch x 1312 halves), swizzled LDS writes ----
    {
        const int grp = threadIdx.x >> 4;
        const int l16 = threadIdx.x & 15;
        const size_t rowbase = ((size_t)(chgrp * 16 + grp) * NBATCH + bb) * PADP
                             + (size_t)tg * 1024 + 8;   // abs col of xs[.][0]
#pragma unroll
        for (int it = 0; it < 11; ++it) {
            const int chunk = l16 + 16 * it;
            if (chunk < 164) {
                const half8 v = *reinterpret_cast<const half8*>(xT + rowbase + (size_t)chunk * 8);
                *reinterpret_cast<half8*>(smem + (size_t)grp * XROWB + swz(chunk * 16)) = v;
            }
        }
    }
    __syncthreads();

    const int wid = threadIdx.x >> 6, lane = threadIdx.x & 63;
    const int j32 = lane & 31, h = lane >> 5;
    const int c0 = chgrp * 16 + wid * 4;

    f32x16 acc[4];
#pragma unroll
    for (int q = 0; q < 4; ++q)
#pragma unroll
        for (int r = 0; r < 16; ++r) acc[q][r] = 0.0f;

#pragma unroll
    for (int w = 0; w < NW2; ++w) {
        const int bir = swz(576 - 32 * w + 64 * j32 + 16 * h);   // byte in row
#pragma unroll
        for (int q = 0; q < 4; ++q) {
            const half8 a = *reinterpret_cast<const half8*>(
                afr + ((size_t)((c0 + q) * NW2 + w) * 64 + lane) * 8);
            const half8 bv = *reinterpret_cast<const half8*>(
                smem + (size_t)(wid * 4 + q) * XROWB + bir);
            acc[q] = __builtin_amdgcn_mfma_f32_32x32x16_f16(a, bv, acc[q], 0, 0, 0);
        }
    }

    // ---- epilogue: per 256-tile, gelu -> lout (aliases xs) -> float4 stores ----
    const int cq  = threadIdx.x & 3;
    const int nr0 = threadIdx.x >> 2;        // 0..63
#pragma unroll
    for (int ti = 0; ti < 4; ++ti) {
        __syncthreads();                     // xs reads (ti=0) / prev store reads done
        if ((j32 >> 3) == ti) {
#pragma unroll
            for (int q = 0; q < 4; ++q) {
#pragma unroll
                for (int rg = 0; rg < 4; ++rg) {
                    f32x4 o;
#pragma unroll
                    for (int r = 0; r < 4; ++r) {
                        const float y  = acc[q][4 * rg + r];
                        const float wv = fmaf(y * y, 0.14270963f, 1.5957691f);
                        const float e  = __expf(y * wv);
                        o[r] = y - y * __builtin_amdgcn_rcpf(e + 1.0f);
                    }
                    // i = (reg&3) + 8*rg + 4*h -> n_rel = 32*(j&7) + 8*rg + 4*h + r
                    *reinterpret_cast<f32x4*>(smem + (size_t)(wid * 4 + q) * LOWB
                                              + 4 * (32 * (j32 & 7) + 8 * rg + 4 * h)) = o;
                }
            }
        }
        __syncthreads();
        float* obp = out + ((size_t)bb * LSEQ + tg * 1024 + ti * 256) * CH + chgrp * 16 + 4 * cq;
#pragma unroll
        for (int it = 0; it < 4; ++it) {
            const int n = nr0 + 64 * it;
            f32x4 o;
            o[0] = *reinterpret_cast<const float*>(smem + (size_t)(4 * cq + 0) * LOWB + 4 * n);
            o[1] = *reinterpret_cast<const float*>(smem + (size_t)(4 * cq + 1) * LOWB + 4 * n);
            o[2] = *reinterpret_cast<const float*>(smem + (size_t)(4 * cq + 2) * LOWB + 4 * n);
            o[3] = *reinterpret_cast<const float*>(smem + (size_t)(4 * cq + 3) * LOWB + 4 * n);
            *reinterpret_cast<f32x4*>(obp + (size_t)n * CH) = o;
        }
    }
}

// ======================== FALLBACK (R5, proven 138us) =======================
#define RINGF 32
#define CPBF  256
__global__ __launch_bounds__(ORDER) void rtf_impulse_fb(const float* __restrict__ A,
                                                        const float* __restrict__ B,
                                                        const float* __restrict__ h0,
                                                        float* __restrict__ kt4) {
    const int c = blockIdx.x, lane = threadIdx.x;
    const float a = A[c * ORDER + lane], bc = B[c * ORDER + lane], h0v = h0[0];
    float s = 0.0f;
    for (int t = 0; t < KTAP; ++t) {
        const float s1 = __shfl(s, 0);
        const float bt = (t < ORDER) ? __shfl(bc, t) : 0.0f;
        const float y  = bt + s1;
        float su = __shfl_down(s, 1);
        if (lane == ORDER - 1) su = 0.0f;
        s = su - a * y;
        if (lane == 0) kt4[((size_t)(t >> 2) * CH + c) * 4 + (t & 3)] = (t == 0) ? (y + h0v) : y;
    }
}
__global__ __launch_bounds__(CPBF) void fir_gelu_fb(const float* __restrict__ x,
                                                    const float* __restrict__ kt4,
                                                    float* __restrict__ out) {
    const int h = blockIdx.x;
    const int logical = ((h & 7) << 8) | (h >> 3);
    const int tile = logical & 255, sl = logical >> 8;
    const int cb = sl & 1, b = sl >> 1;
    const int c = cb * CPBF + threadIdx.x;
    const int n0 = tile * RINGF;
    const float* xb = x + (size_t)b * LSEQ * CH + c;
    const float4* kt4v = (const float4*)kt4;
    float acc[RINGF]; float ring[RINGF]; float px[2][8]; float kbuf[2][8];
#pragma unroll
    for (int r = 0; r < RINGF; ++r) acc[r] = 0.0f;
#pragma unroll
    for (int i = 0; i < RINGF; ++i) ring[i] = xb[(size_t)(n0 + i) * CH];
    {
        const float4 ka = kt4v[(size_t)0 * CH + c];
        const float4 kb = kt4v[(size_t)1 * CH + c];
        kbuf[0][0] = ka.x; kbuf[0][1] = ka.y; kbuf[0][2] = ka.z; kbuf[0][3] = ka.w;
        kbuf[0][4] = kb.x; kbuf[0][5] = kb.y; kbuf[0][6] = kb.z; kbuf[0][7] = kb.w;
#pragma unroll
        for (int g2 = 0; g2 < 8; ++g2) {
            const int m = n0 - 1 - g2;
            px[0][g2] = (m >= 0) ? xb[(size_t)m * CH] : 0.0f;
        }
    }
    for (int tb = 0; tb < KTAP; tb += RINGF) {
#pragma unroll
        for (int qq = 0; qq < 4; ++qq) {
            const int cur = qq & 1, nxt = cur ^ 1;
            const int tn = tb + 8 * (qq + 1);
            if (tn < KTAP) {
                const float4 ka = kt4v[(size_t)(tn >> 2) * CH + c];
                const float4 kb = kt4v[(size_t)((tn >> 2) + 1) * CH + c];
                kbuf[nxt][0] = ka.x; kbuf[nxt][1] = ka.y; kbuf[nxt][2] = ka.z; kbuf[nxt][3] = ka.w;
                kbuf[nxt][4] = kb.x; kbuf[nxt][5] = kb.y; kbuf[nxt][6] = kb.z; kbuf[nxt][7] = kb.w;
#pragma unroll
                for (int g2 = 0; g2 < 8; ++g2) {
                    const int m = n0 - tn - 1 - g2;
                    px[nxt][g2] = (m >= 0) ? xb[(size_t)m * CH] : 0.0f;
                }
            }
#pragma unroll
            for (int g2 = 0; g2 < 8; ++g2) {
                const int tq = 8 * qq + g2;
                const float kv = kbuf[cur][g2];
#pragma unroll
                for (int r = 0; r < RINGF; ++r)
                    acc[r] = fmaf(kv, ring[(r - tq) & (RINGF - 1)], acc[r]);
                ring[(RINGF - 1 - tq) & (RINGF - 1)] = px[cur][g2];
            }
        }
    }
    float* ob = out + ((size_t)b * LSEQ + n0) * CH + c;
#pragma unroll
    for (int r = 0; r < RINGF; ++r) {
        const float y = acc[r];
        const float wv = fmaf(y * y, 0.14270963f, 1.5957691f);
        const float e = __expf(y * wv);
        ob[(size_t)r * CH] = y - y * __builtin_amdgcn_rcpf(e + 1.0f);
    }
}

extern "C" void kernel_launch(void* const* d_in, const int* in_sizes, int n_in,
                              void* d_out, int out_size, void* d_ws, size_t ws_size,
                              hipStream_t stream) {
    const float* x  = (const float*)d_in[0];
    const float* A  = (const float*)d_in[1];
    const float* B  = (const float*)d_in[2];
    const float* h0 = (const float*)d_in[3];
    float* out = (float*)d_out;

    if (ws_size >= WS_NEED) {
        _Float16* afr = (_Float16*)d_ws;
        _Float16* xT  = afr + AFRAG_HALFS;
        prep<<<dim3(NAPREP + NXPOSE), dim3(256), 0, stream>>>(A, B, h0, x, afr, xT);
        fir_mfma<<<dim3(1024), dim3(256), 0, stream>>>(xT, afr, out);
    } else {
        float* kt4 = (float*)d_ws;  // 512 KB
        rtf_impulse_fb<<<dim3(CH), dim3(ORDER), 0, stream>>>(A, B, h0, kt4);
        fir_gelu_fb<<<dim3((LSEQ / RINGF) * (CH / CPBF) * NBATCH), dim3(CPBF), 0, stream>>>(x, kt4, out);
    }
}

// Round 18
// 58.735 us; speedup vs baseline: 1.2542x; 1.2542x over previous
//
#include <hip/hip_runtime.h>
#include <stdint.h>

// Problem constants: x (4, 8192, 512) f32, A/B (512, 64), h0 scalar.
#define NBATCH 4
#define LSEQ   8192
#define CH     512
#define ORDER  64
#define KTAP   256           // recursion length; windows cover taps <= 239+i (tail ~6e-7, invisible)

typedef _Float16 half8 __attribute__((ext_vector_type(8)));
typedef _Float16 half4 __attribute__((ext_vector_type(4)));
typedef float    f32x4 __attribute__((ext_vector_type(4)));

// Transposed/padded x geometry: column p = PAD0 + row, zeros outside [0,8192).
#define PADP  8512
#define PAD0  279
// NW=8 (was 9): row i covers taps [i-16, 239+i] each exactly once; taps beyond
// 239+i are ~r^240 ~ 6e-7 — invisible vs 1.95e-3 measured absmax (R3-R17:
// KTAP 384 vs 256 gave identical absmax). -11% MFMA and -11% LDS reads (the
// binding pipe, R16 post-mortem).
#define NW    8

#define AFRAG_HALFS  ((size_t)CH * NW * 64 * 8)        // 4.2 MB
#define XT_HALFS     ((size_t)CH * NBATCH * PADP)      // 34.9 MB
#define WS_NEED      ((AFRAG_HALFS + XT_HALFS) * 2)

#define NAPREP 128                       // afrag blocks (4 ch each)
#define NXPOSE (133 * 8 * NBATCH)        // xpose blocks (PADP/64 x CH/64 x B)

// fir LDS: xs[16 ch][1312 halves] (2624 B row stride), lout[16][260 f32]
// ALIASED onto xs (xs dead after MFMA loop; epilogue barrier orders it).
#define XROWB 2624
#define SMEMB (16 * XROWB)   // 41984 B -> 3 blocks/CU
#define LOWB  1040

// ---------------------------------------------------------------------------
// Kernel 1 (fused prep, PROVEN R8/R16): blocks [0,128) build per-channel MFMA
// A-fragments (IIR impulse response, 4 ch/block); blocks [128,128+4256)
// transpose x to xT[c*4+b][p] f16 zero-padded (64x64 LDS tile).
// ---------------------------------------------------------------------------
__global__ __launch_bounds__(256) void prep(const float* __restrict__ A,
                                            const float* __restrict__ B,
                                            const float* __restrict__ h0,
                                            const float* __restrict__ x,
                                            _Float16* __restrict__ afr,
                                            _Float16* __restrict__ xT) {
    __shared__ float    Ksh[4][KTAP];
    __shared__ _Float16 tile[64][74];
    const int bid = blockIdx.x;
    if (bid < NAPREP) {
        // A_w[i][k] = Kx[32w+15+i-k], lane l: i=l&15, k=8*(l>>4)+e; h0 folded
        // into Kx[0]; Kx zero outside [0,KTAP).
        const int wv = threadIdx.x >> 6, lane = threadIdx.x & 63;
        const int c  = bid * 4 + wv;
        const float a  = A[c * ORDER + lane];
        const float bc = B[c * ORDER + lane];
        const float h0v = h0[0];
        float s = 0.0f;
        for (int t = 0; t < KTAP; ++t) {
            const float s1 = __shfl(s, 0);
            const float bt = (t < ORDER) ? __shfl(bc, t) : 0.0f;
            const float y  = bt + s1;
            float su = __shfl_down(s, 1);
            if (lane == ORDER - 1) su = 0.0f;
            s = su - a * y;
            if (lane == 0) Ksh[wv][t] = (t == 0) ? (y + h0v) : y;
        }
        __syncthreads();
        const int i = lane & 15, g = lane >> 4;
        for (int w = 0; w < NW; ++w) {
            half8 hv;
#pragma unroll
            for (int e = 0; e < 8; ++e) {
                const int t = 32 * w + 15 + i - 8 * g - e;
                hv[e] = (_Float16)((t >= 0 && t < KTAP) ? Ksh[wv][t] : 0.0f);
            }
            *reinterpret_cast<half8*>(afr + ((size_t)(c * NW + w) * 64 + lane) * 8) = hv;
        }
    } else {
        // transpose: x (b,n,c) f32 -> xT (c*4+b, p) f16, zero-padded
        const int bid2 = bid - NAPREP;
        const int px   = bid2 % 133;
        const int cy   = (bid2 / 133) & 7;
        const int bz   = bid2 / (133 * 8);
        const int p0 = px * 64, c0 = cy * 64, t = threadIdx.x;
        const int cl = (t & 15) * 4;
        const int rl = t >> 4;
#pragma unroll
        for (int pass = 0; pass < 4; ++pass) {
            const int pl = rl + 16 * pass;
            const int r  = p0 + pl - PAD0;
            float4 v = {0.0f, 0.0f, 0.0f, 0.0f};
            if (r >= 0 && r < LSEQ)
                v = *reinterpret_cast<const float4*>(x + ((size_t)bz * LSEQ + r) * CH + c0 + cl);
            tile[pl][cl + 0] = (_Float16)v.x;
            tile[pl][cl + 1] = (_Float16)v.y;
            tile[pl][cl + 2] = (_Float16)v.z;
            tile[pl][cl + 3] = (_Float16)v.w;
        }
        __syncthreads();
        const int pl2 = (t & 15) * 4;
#pragma unroll
        for (int pass = 0; pass < 4; ++pass) {
            const int cc = (t >> 4) + 16 * pass;
            half4 hv;
#pragma unroll
            for (int d = 0; d < 4; ++d) hv[d] = tile[pl2 + d][cc];
            *reinterpret_cast<half4*>(xT + ((size_t)((c0 + cc) * NBATCH + bz)) * PADP + p0 + pl2) = hv;
        }
    }
}

// ---------------------------------------------------------------------------
// Kernel 2: FIR as banded-Toeplitz MFMA + gelu, LDS-staged xT (R16 structure,
// session best 60.16us total), with NW=8. Block = 16 ch x 1024 n (4 tiles of
// 256) x 1 batch. Grid 1024, chgrp-major XCD swizzle. Main loop w-outer/
// tile-inner: A-frag global (L2), B-frag ds_read_b128 1:1 MFMA, acc[4][4].
// lout aliased onto xs (3 blocks/CU), float4 gather-stores.
// ---------------------------------------------------------------------------
__global__ __launch_bounds__(256) void fir_mfma(const _Float16* __restrict__ xT,
                                                const _Float16* __restrict__ afr,
                                                float* __restrict__ out) {
    __shared__ __align__(16) char smem[SMEMB];          // xs; lout aliases it
    const int gid     = blockIdx.x;
    const int logical = (gid & 7) * 128 + (gid >> 3);   // bijective (1024%8==0)
    const int chgrp   = logical >> 5;                   // 0..31 (XCD-local slab)
    const int rem     = logical & 31;
    const int bb      = rem >> 3;
    const int tg      = rem & 7;

    // ---- stage x window: 16 groups of 16 threads, one channel each ----
    {
        const int grp = threadIdx.x >> 4;
        const int l16 = threadIdx.x & 15;
        const size_t rowbase = ((size_t)(chgrp * 16 + grp) * NBATCH + bb) * PADP
                             + (size_t)tg * 1024 + 8;   // abs col of xs[.][0]
#pragma unroll
        for (int it = 0; it < 11; ++it) {
            const int chunk = l16 + 16 * it;
            if (chunk < 164) {
                const half8 v = *reinterpret_cast<const half8*>(xT + rowbase + (size_t)chunk * 8);
                *reinterpret_cast<half8*>(smem + (size_t)grp * XROWB + chunk * 16) = v;
            }
        }
    }
    __syncthreads();

    const int wid = threadIdx.x >> 6, lane = threadIdx.x & 63;
    const int j = lane & 15, g = lane >> 4;
    const int c0 = chgrp * 16 + wid * 4;
    const _Float16* af = afr + (size_t)lane * 8;

    f32x4 acc[4][4];
#pragma unroll
    for (int ti = 0; ti < 4; ++ti)
#pragma unroll
        for (int q = 0; q < 4; ++q) acc[ti][q] = (f32x4){0.f, 0.f, 0.f, 0.f};

#pragma unroll
    for (int w = 0; w < NW; ++w) {
        half8 a[4];
#pragma unroll
        for (int q = 0; q < 4; ++q)
            a[q] = *reinterpret_cast<const half8*>(af + (size_t)((c0 + q) * NW + w) * 512);
        const int base = 16 * j + 8 * g - 32 * w + 256;   // xs idx of B-frag, tile 0
#pragma unroll
        for (int ti = 0; ti < 4; ++ti) {
#pragma unroll
            for (int q = 0; q < 4; ++q) {
                const half8 bv = *reinterpret_cast<const half8*>(
                    smem + (size_t)(wid * 4 + q) * XROWB + 2 * (base + 256 * ti));
                acc[ti][q] = __builtin_amdgcn_mfma_f32_16x16x32_f16(a[q], bv, acc[ti][q], 0, 0, 0);
            }
        }
    }

    // ---- epilogue: per tile, gelu -> lout (ALIASES xs) -> float4 stores ----
    const int cq  = threadIdx.x & 3;
    const int nr0 = threadIdx.x >> 2;        // 0..63
#pragma unroll
    for (int ti = 0; ti < 4; ++ti) {
        __syncthreads();                     // xs reads (ti=0) / prev store reads done
#pragma unroll
        for (int q = 0; q < 4; ++q) {
            f32x4 o;
#pragma unroll
            for (int r = 0; r < 4; ++r) {
                const float y  = acc[ti][q][r];
                const float wv = fmaf(y * y, 0.14270963f, 1.5957691f);
                const float e  = __expf(y * wv);
                o[r] = y - y * __builtin_amdgcn_rcpf(e + 1.0f);
            }
            *reinterpret_cast<f32x4*>(smem + (size_t)(wid * 4 + q) * LOWB
                                      + 4 * (16 * j + 4 * g)) = o;
        }
        __syncthreads();
        float* obp = out + ((size_t)bb * LSEQ + tg * 1024 + ti * 256) * CH + chgrp * 16 + 4 * cq;
#pragma unroll
        for (int it = 0; it < 4; ++it) {
            const int n = nr0 + 64 * it;
            f32x4 o;
            o[0] = *reinterpret_cast<const float*>(smem + (size_t)(4 * cq + 0) * LOWB + 4 * n);
            o[1] = *reinterpret_cast<const float*>(smem + (size_t)(4 * cq + 1) * LOWB + 4 * n);
            o[2] = *reinterpret_cast<const float*>(smem + (size_t)(4 * cq + 2) * LOWB + 4 * n);
            o[3] = *reinterpret_cast<const float*>(smem + (size_t)(4 * cq + 3) * LOWB + 4 * n);
            *reinterpret_cast<f32x4*>(obp + (size_t)n * CH) = o;
        }
    }
}

// ======================== FALLBACK (R5, proven 138us) =======================
#define RINGF 32
#define CPBF  256
__global__ __launch_bounds__(ORDER) void rtf_impulse_fb(const float* __restrict__ A,
                                                        const float* __restrict__ B,
                                                        const float* __restrict__ h0,
                                                        float* __restrict__ kt4) {
    const int c = blockIdx.x, lane = threadIdx.x;
    const float a = A[c * ORDER + lane], bc = B[c * ORDER + lane], h0v = h0[0];
    float s = 0.0f;
    for (int t = 0; t < KTAP; ++t) {
        const float s1 = __shfl(s, 0);
        const float bt = (t < ORDER) ? __shfl(bc, t) : 0.0f;
        const float y  = bt + s1;
        float su = __shfl_down(s, 1);
        if (lane == ORDER - 1) su = 0.0f;
        s = su - a * y;
        if (lane == 0) kt4[((size_t)(t >> 2) * CH + c) * 4 + (t & 3)] = (t == 0) ? (y + h0v) : y;
    }
}
__global__ __launch_bounds__(CPBF) void fir_gelu_fb(const float* __restrict__ x,
                                                    const float* __restrict__ kt4,
                                                    float* __restrict__ out) {
    const int h = blockIdx.x;
    const int logical = ((h & 7) << 8) | (h >> 3);
    const int tile = logical & 255, sl = logical >> 8;
    const int cb = sl & 1, b = sl >> 1;
    const int c = cb * CPBF + threadIdx.x;
    const int n0 = tile * RINGF;
    const float* xb = x + (size_t)b * LSEQ * CH + c;
    const float4* kt4v = (const float4*)kt4;
    float acc[RINGF]; float ring[RINGF]; float px[2][8]; float kbuf[2][8];
#pragma unroll
    for (int r = 0; r < RINGF; ++r) acc[r] = 0.0f;
#pragma unroll
    for (int i = 0; i < RINGF; ++i) ring[i] = xb[(size_t)(n0 + i) * CH];
    {
        const float4 ka = kt4v[(size_t)0 * CH + c];
        const float4 kb = kt4v[(size_t)1 * CH + c];
        kbuf[0][0] = ka.x; kbuf[0][1] = ka.y; kbuf[0][2] = ka.z; kbuf[0][3] = ka.w;
        kbuf[0][4] = kb.x; kbuf[0][5] = kb.y; kbuf[0][6] = kb.z; kbuf[0][7] = kb.w;
#pragma unroll
        for (int g2 = 0; g2 < 8; ++g2) {
            const int m = n0 - 1 - g2;
            px[0][g2] = (m >= 0) ? xb[(size_t)m * CH] : 0.0f;
        }
    }
    for (int tb = 0; tb < KTAP; tb += RINGF) {
#pragma unroll
        for (int qq = 0; qq < 4; ++qq) {
            const int cur = qq & 1, nxt = cur ^ 1;
            const int tn = tb + 8 * (qq + 1);
            if (tn < KTAP) {
                const float4 ka = kt4v[(size_t)(tn >> 2) * CH + c];
                const float4 kb = kt4v[(size_t)((tn >> 2) + 1) * CH + c];
                kbuf[nxt][0] = ka.x; kbuf[nxt][1] = ka.y; kbuf[nxt][2] = ka.z; kbuf[nxt][3] = ka.w;
                kbuf[nxt][4] = kb.x; kbuf[nxt][5] = kb.y; kbuf[nxt][6] = kb.z; kbuf[nxt][7] = kb.w;
#pragma unroll
                for (int g2 = 0; g2 < 8; ++g2) {
                    const int m = n0 - tn - 1 - g2;
                    px[nxt][g2] = (m >= 0) ? xb[(size_t)m * CH] : 0.0f;
                }
            }
#pragma unroll
            for (int g2 = 0; g2 < 8; ++g2) {
                const int tq = 8 * qq + g2;
                const float kv = kbuf[cur][g2];
#pragma unroll
                for (int r = 0; r < RINGF; ++r)
                    acc[r] = fmaf(kv, ring[(r - tq) & (RINGF - 1)], acc[r]);
                ring[(RINGF - 1 - tq) & (RINGF - 1)] = px[cur][g2];
            }
        }
    }
    float* ob = out + ((size_t)b * LSEQ + n0) * CH + c;
#pragma unroll
    for (int r = 0; r < RINGF; ++r) {
        const float y = acc[r];
        const float wv = fmaf(y * y, 0.14270963f, 1.5957691f);
        const float e = __expf(y * wv);
        ob[(size_t)r * CH] = y - y * __builtin_amdgcn_rcpf(e + 1.0f);
    }
}

extern "C" void kernel_launch(void* const* d_in, const int* in_sizes, int n_in,
                              void* d_out, int out_size, void* d_ws, size_t ws_size,
                              hipStream_t stream) {
    const float* x  = (const float*)d_in[0];
    const float* A  = (const float*)d_in[1];
    const float* B  = (const float*)d_in[2];
    const float* h0 = (const float*)d_in[3];
    float* out = (float*)d_out;

    if (ws_size >= WS_NEED) {
        _Float16* afr = (_Float16*)d_ws;
        _Float16* xT  = afr + AFRAG_HALFS;
        prep<<<dim3(NAPREP + NXPOSE), dim3(256), 0, stream>>>(A, B, h0, x, afr, xT);
        fir_mfma<<<dim3(1024), dim3(256), 0, stream>>>(xT, afr, out);
    } else {
        float* kt4 = (float*)d_ws;  // 512 KB
        rtf_impulse_fb<<<dim3(CH), dim3(ORDER), 0, stream>>>(A, B, h0, kt4);
        fir_gelu_fb<<<dim3((LSEQ / RINGF) * (CH / CPBF) * NBATCH), dim3(CPBF), 0, stream>>>(x, kt4, out);
    }
}